// Round 3
// baseline (131.314 us; speedup 1.0000x reference)
//
#include <hip/hip_runtime.h>
#include <stdint.h>

typedef unsigned long long u64;
typedef unsigned int u32;

#define N_ANCH 36864
#define WGRID 64
#define A_PER 9
#define KTOP 6000
#define NOUT 300
#define NBIN 5120       // max used bin = 4352 (binof), multiple of 1024 for scan
#define NCHK 94         // ceil(6000/64) = u64 words
#define NJ   6016       // padded j-stride of S (u64 words, 64-multiple >= 6000)
#define INF_BIN 0       // -inf / invalid scores
#define PCAP 6          // per-wave word slots: w = wave + 16*k, k<6 covers w<94

// Raw barrier: LDS-drain only (HK/m201 pattern). Global loads stay in flight across it —
// __syncthreads() would emit s_waitcnt vmcnt(0) and serialize every prefetch (round-2 bug).
#define BARRIER_LDS() do {                                   \
    asm volatile("s_waitcnt lgkmcnt(0)" ::: "memory");       \
    __builtin_amdgcn_s_barrier();                            \
    asm volatile("" ::: "memory");                           \
} while (0)

// Base anchors from py-faster-rcnn generate_anchors (scales 8,16,32; ratios .5,1,2), exact integers.
__constant__ float c_ax1[9] = {-84.f,-176.f,-360.f,-56.f,-120.f,-248.f,-36.f,-80.f,-168.f};
__constant__ float c_ay1[9] = {-40.f,-88.f,-184.f,-56.f,-120.f,-248.f,-80.f,-168.f,-344.f};
__constant__ float c_aw[9]  = {184.f,368.f,736.f,128.f,256.f,512.f,88.f,176.f,352.f};
__constant__ float c_ah[9]  = {96.f,192.f,384.f,128.f,256.f,512.f,176.f,352.f,704.f};

// Monotone (order-preserving) bin of the ordered-float score word u = key>>32.
__device__ __forceinline__ u32 binof(u32 u) {
    if (u < 0x80000000u) return 0u;                          // -inf (invalid)
    if (u < 0xBF000000u) return 1u + ((u - 0x80000000u) >> 22);   // s<0.5 : 1..252
    return 256u + ((u - 0xBF000000u) >> 11);                 // s>=0.5: 256..4352
}

// 144 blocks x 256 threads = 36864.
__global__ __launch_bounds__(256) void proposal_kernel(const float* __restrict__ cls,
                                                       const float* __restrict__ dlt,
                                                       u64* __restrict__ keys,
                                                       float4* __restrict__ boxes,
                                                       u32* __restrict__ hist) {
    __shared__ u32 lh[NBIN];
    const int t = threadIdx.x;
    for (int b = t; b < NBIN; b += 256) lh[b] = 0;
    __syncthreads();

    int i = blockIdx.x * 256 + t;
    int a  = i % A_PER;
    int hw = i / A_PER;
    int wx = hw % WGRID;
    int hy = hw / WGRID;

    float2 lp = *(const float2*)(cls + hw * 18 + 2 * a);
    float l0 = lp.x, l1 = lp.y;
    float m  = fmaxf(l0, l1);
    float e0 = expf(l0 - m), e1 = expf(l1 - m);
    float s  = e1 / (e0 + e1);

    float4 dd = *(const float4*)(dlt + hw * 36 + 4 * a);
    float dx = dd.x, dy = dd.y, dw = dd.z, dh = dd.w;
    float aw = c_aw[a], ah = c_ah[a];
    float axc = (c_ax1[a] + 16.f * (float)wx) + 0.5f * aw;
    float ayc = (c_ay1[a] + 16.f * (float)hy) + 0.5f * ah;

    float pxc = dx * aw + axc;
    float pyc = dy * ah + ayc;
    float pw  = expf(dw) * aw;
    float ph  = expf(dh) * ah;
    float x1 = pxc - 0.5f * pw, y1 = pyc - 0.5f * ph;
    float x2 = pxc + 0.5f * pw, y2 = pyc + 0.5f * ph;
    x1 = fminf(fmaxf(x1, 0.f), 1023.f);
    x2 = fminf(fmaxf(x2, 0.f), 1023.f);
    y1 = fminf(fmaxf(y1, 0.f), 1023.f);
    y2 = fminf(fmaxf(y2, 0.f), 1023.f);
    bool valid = ((x2 - x1 + 1.f) >= 16.f) && ((y2 - y1 + 1.f) >= 16.f);
    float sc = valid ? s : -__builtin_huge_valf();

    u32 sb  = __float_as_uint(sc);
    u32 ord = (sb & 0x80000000u) ? ~sb : (sb | 0x80000000u);
    u64 key = ((u64)ord << 32) | (u32)(~(u32)i);
    keys[i]  = key;
    boxes[i] = make_float4(x1, y1, x2, y2);

    u64 infb = __ballot(!valid);
    if (valid) {
        atomicAdd(&lh[binof(ord)], 1u);
    } else {
        int lane = t & 63;
        if (lane == __builtin_ctzll(infb))
            atomicAdd(&lh[INF_BIN], (u32)__popcll(infb));
    }
    __syncthreads();
    for (int b = t; b < NBIN; b += 256) {
        u32 v = lh[b];
        if (v) atomicAdd(&hist[b], v);
    }
}

// Descending exclusive prefix over NBIN bins via shfl wave-scan (1 barrier, was 20).
__global__ __launch_bounds__(1024) void scan_kernel(const u32* __restrict__ hist,
                                                    u32* __restrict__ binStart,
                                                    u32* __restrict__ gEV) {
    __shared__ u32 wsum[16];
    const int t = threadIdx.x;
    const int lane = t & 63;
    const int v = t >> 6;
    if (t == 0) gEV[1] = KTOP;
    int hi = NBIN - 1 - 5 * t;   // thread t owns bins [hi-4 .. hi], descending
    u32 cnt[5];
    u32 sum = 0;
#pragma unroll
    for (int k = 0; k < 5; ++k) { cnt[k] = hist[hi - k]; sum += cnt[k]; }
    u32 s = sum;                 // inclusive wave scan (thread order == descending bins)
#pragma unroll
    for (int d = 1; d < 64; d <<= 1) {
        u32 x = __shfl_up(s, d, 64);
        if (lane >= d) s += x;
    }
    if (lane == 63) wsum[v] = s;
    __syncthreads();
    u32 base = 0;
#pragma unroll
    for (int q = 0; q < 16; ++q) {
        u32 x = wsum[q];
        if (q < v) base += x;
    }
    u32 run = base + s - sum;    // exclusive (sum of all higher bins)
#pragma unroll
    for (int k = 0; k < 5; ++k) {
        int b = hi - k;
        binStart[b] = run;
        u32 end = run + cnt[k];
        if (run < KTOP && end >= KTOP) gEV[0] = end;   // unique boundary bucket
        run = end;
    }
}

__global__ void scatter_kernel(const u64* __restrict__ keys,
                               const u32* __restrict__ binStart,
                               u32* __restrict__ cursor,
                               u64* __restrict__ scat) {
    int i = blockIdx.x * blockDim.x + threadIdx.x;
    if (i >= N_ANCH) return;
    u64 k = keys[i];
    u32 b = binof((u32)(k >> 32));
    u32 s = binStart[b];
    if (s < KTOP) {
        u32 p = s + atomicAdd(&cursor[b], 1u);
        scat[p] = k;
    }
}

__global__ void rank_kernel(const u64* __restrict__ scat,
                            const u32* __restrict__ binStart,
                            const u32* __restrict__ hist,
                            const float4* __restrict__ boxes,
                            const u32* __restrict__ gEV,
                            float4* __restrict__ topBoxes,
                            int* __restrict__ gV) {
    int i = blockIdx.x * blockDim.x + threadIdx.x;
    u32 E = gEV[0];
    if (i >= (int)E) return;
    u64 k = scat[i];
    u32 b = binof((u32)(k >> 32));
    u32 s = binStart[b], c = hist[b];
    u32 r = s;
    for (u32 j = s; j < s + c; ++j) r += (scat[j] > k) ? 1u : 0u;
    if (r < KTOP) {
        int idx = (int)(~(u32)k);
        topBoxes[r] = boxes[idx];
        if (!(k >> 63)) atomicMin(gV, (int)r);
    }
}

__device__ __forceinline__ bool iou_gt(float4 a, float areaA, float4 b, float areaB) {
    float ix1 = fmaxf(a.x, b.x), iy1 = fmaxf(a.y, b.y);
    float ix2 = fminf(a.z, b.z), iy2 = fminf(a.w, b.w);
    float iw = fmaxf(ix2 - ix1 + 1.0f, 0.0f);
    float ih = fmaxf(iy2 - iy1 + 1.0f, 0.0f);
    float inter = iw * ih;
    float iou = inter / (areaA + areaB - inter);
    return iou > 0.7f;
}

// TRANSPOSED suppression mask: S[w][j] bit b = (IoU(box_{64w+b}, box_j) > 0.7) && (64w+b < j).
__global__ __launch_bounds__(256) void maskT_kernel(const float4* __restrict__ topBoxes,
                                                    const u32* __restrict__ gEV,
                                                    u64* __restrict__ S) {
    const int V = (int)gEV[1];
    const int nch = (V + 63) >> 6;
    const int jc = blockIdx.x;               // j-chunk (column group of 64 boxes)
    const int w0 = blockIdx.y * 4;           // first i-word of this block
    if (jc >= nch || w0 > jc) return;        // only w <= jc needed (i < j)
    __shared__ float4 cb[256];
    __shared__ float  ca[256];
    const int t = threadIdx.x;
    const int lane = t & 63;
    {
        int ci = w0 * 64 + t;
        float4 b = (ci < V) ? topBoxes[ci] : make_float4(0.f, 0.f, -8.f, -8.f);
        cb[t] = b;
        ca[t] = (b.z - b.x + 1.f) * (b.w - b.y + 1.f);
    }
    __syncthreads();
    const int w = w0 + (t >> 6);
    if (w > jc || w >= nch) return;
    const int j = jc * 64 + lane;
    float4 bj = (j < V) ? topBoxes[j] : make_float4(0.f, 0.f, -8.f, -8.f);
    float aj = (bj.z - bj.x + 1.f) * (bj.w - bj.y + 1.f);
    const int s0 = (t >> 6) * 64;
    u64 m = 0;
#pragma unroll 4
    for (int b = 0; b < 64; ++b)
        if (iou_gt(bj, aj, cb[s0 + b], ca[s0 + b])) m |= (1ull << b);
    if (w == jc) m &= ((1ull << lane) - 1ull);   // diagonal word: keep only i < j
    S[(u64)w * NJ + j] = m;
}

// Single block, 1024 threads, EXACT greedy NMS over the transposed mask.
// ONE raw barrier per round: every wave resolves the chunk REDUNDANTLY (identical
// inputs -> identical kb), so keepw/nkept/kw are wave-local; the only cross-wave
// data is supw, double-buffered by round parity (WAR separated by next round's
// barrier). Raw barrier = LDS-drain only, so the depth-2 pend prefetches (addresses
// independent of which boxes get kept) stay in flight across ~2 rounds.
__global__ __launch_bounds__(1024) void nms_out_kernel(const float4* __restrict__ topBoxes,
                                                       const u32* __restrict__ gEV,
                                                       const u64* __restrict__ S,
                                                       float* __restrict__ out) {
    __shared__ u64 keepw[NCHK];
    __shared__ u64 supw[2][16];
    __shared__ u32 wsum[16];
    const int t = threadIdx.x;
    const int lane = t & 63;
    const int v = t >> 6;                    // wave id, 16 waves
    if (t < NCHK) keepw[t] = 0;
    const int V = (int)gEV[1];
    const int nch = (V + 63) >> 6;

    u64 kw[PCAP], pendE[PCAP], pendO[PCAP];  // kept-words (local) + parity-buffered S words
#pragma unroll
    for (int k = 0; k < PCAP; ++k) { kw[k] = 0; pendE[k] = 0; pendO[k] = 0; }
    u64 dtE = 0, dtO = 0;                    // diagonal words (every wave loads its own copy)
    // prologue: round 0 needs no prior words; round 1 needs w=0 only
#pragma unroll
    for (int k = 0; k < PCAP; ++k) {
        int w = v + 16 * k;
        if (w < 1 && 1 < nch) pendO[k] = S[(u64)w * NJ + 64 + lane];
    }
    dtE = S[lane];                           // diag chunk 0 = S[0][0..63]
    if (nch > 1) dtO = S[(u64)NJ + 64 + lane];   // diag chunk 1 = S[1][64..127]
    int nkept = 0;                           // identical across all waves

    for (int c = 0; c < nch; ++c) {
        const int par = c & 1;
        // suppressed-by-earlier-chunks bits for this wave's words
        u64 acc = 0;
        if (par) {
#pragma unroll
            for (int k = 0; k < PCAP; ++k) { int w = v + 16 * k; if (w < c) acc |= pendO[k] & kw[k]; }
        } else {
#pragma unroll
            for (int k = 0; k < PCAP; ++k) { int w = v + 16 * k; if (w < c) acc |= pendE[k] & kw[k]; }
        }
        u64 bal = __ballot(acc != 0ull);
        if (lane == 0) supw[par][v] = bal;
        // refill just-consumed parity buffer for round c+2 (stays in flight across barrier)
        const int cn = c + 2;
        if (cn < nch) {
            const u64* Sc = S + (u64)cn * 64 + lane;
            if (par) {
#pragma unroll
                for (int k = 0; k < PCAP; ++k) { int w = v + 16 * k; if (w < cn) pendO[k] = Sc[(u64)w * NJ]; }
            } else {
#pragma unroll
                for (int k = 0; k < PCAP; ++k) { int w = v + 16 * k; if (w < cn) pendE[k] = Sc[(u64)w * NJ]; }
            }
        }
        BARRIER_LDS();                       // the ONLY barrier in the round
        // redundant resolve (identical in every wave)
        u64 sup = 0;
#pragma unroll
        for (int q = 0; q < 16; ++q) sup |= supw[par][q];
        int rem = V - c * 64;
        u64 aliveM = (rem >= 64) ? ~0ull : ((1ull << rem) - 1ull);
        u64 cand = ~sup & aliveM;
        u64 dT = par ? dtO : dtE;
        u64 kb = 0;
        while (cand) {
            int b = __builtin_ctzll(cand);
            kb |= (1ull << b);
            cand &= ~(1ull << b);
            cand &= ~__ballot(((dT >> b) & 1ull) != 0ull);
        }
        if (t == 0) keepw[c] = kb;           // for phase 2 only (covered by __syncthreads)
        if (cn < nch) {                      // refill diagonal AFTER use (same parity)
            u64 dload = S[(u64)cn * NJ + (u64)cn * 64 + lane];
            if (par) dtO = dload; else dtE = dload;
        }
        // cache this round's keep-word into the owning slot (static indices)
#pragma unroll
        for (int k = 0; k < PCAP; ++k)
            if (v + 16 * k == c) kw[k] = kb;
        nkept += __popcll(kb);
        if (nkept >= NOUT) break;            // uniform across waves (kb identical)
    }
    __syncthreads();                         // full drain once; keepw visible

    // Phase 2: out[pos] = kept boxes in rank order, then not-kept (suppressed or rank>=V)
    // in rank order, filling up to 300. shfl wave-scan (1 barrier).
    const int per = 6;                       // 1024*6 >= 6000
    int r0 = t * per;
    int r1 = min(r0 + per, KTOP);
    u32 cnt = 0;
    for (int r = r0; r < r1; ++r)
        cnt += (u32)((keepw[r >> 6] >> (r & 63)) & 1ull);
    u32 s = cnt;
#pragma unroll
    for (int d = 1; d < 64; d <<= 1) {
        u32 x = __shfl_up(s, d, 64);
        if (lane >= d) s += x;
    }
    if (lane == 63) wsum[v] = s;
    __syncthreads();
    u32 base = 0;
    u32 total = 0;
#pragma unroll
    for (int q = 0; q < 16; ++q) {
        u32 x = wsum[q];
        if (q < v) base += x;
        total += x;
    }
    const int n1 = min((int)total, NOUT);
    int kp = (int)(base + s - cnt);          // kept before r0
    for (int r = r0; r < r1; ++r) {
        int kept = (int)((keepw[r >> 6] >> (r & 63)) & 1ull);
        int pos = kept ? kp : (n1 + r - kp); // not-kept before r = r - kp
        if (pos < NOUT) {
            float4 b = topBoxes[r];
            out[pos * 5 + 0] = 0.f;
            out[pos * 5 + 1] = b.x;
            out[pos * 5 + 2] = b.y;
            out[pos * 5 + 3] = b.z;
            out[pos * 5 + 4] = b.w;
        }
        kp += kept;
    }
}

extern "C" void kernel_launch(void* const* d_in, const int* in_sizes, int n_in,
                              void* d_out, int out_size, void* d_ws, size_t ws_size,
                              hipStream_t stream) {
    const float* cls = (const float*)d_in[0];   // (1,64,64,18) f32
    const float* dlt = (const float*)d_in[1];   // (1,64,64,36) f32
    float* out = (float*)d_out;                 // 300x5 f32
    char* ws = (char*)d_ws;
    u64*    keys     = (u64*)   (ws);                    // 294912
    u64*    scat     = (u64*)   (ws + 294912);           // 294912
    float4* boxes    = (float4*)(ws + 589824);           // 589824
    float4* topBoxes = (float4*)(ws + 1179648);          // 96000
    u32*    hist     = (u32*)   (ws + 1275648);          // 20480
    u32*    cursor   = (u32*)   (ws + 1296128);          // 20480
    u32*    binStart = (u32*)   (ws + 1316608);          // 20480
    u32*    gEV      = (u32*)   (ws + 1337088);          // [0]=E, [1]=V (+pad)
    u64*    S        = (u64*)   (ws + 1337344);          // 4524032 (94 x 6016 words)

    hipMemsetAsync(hist, 0, 2 * NBIN * sizeof(u32), stream);   // hist + cursor
    proposal_kernel<<<144, 256, 0, stream>>>(cls, dlt, keys, boxes, hist);
    scan_kernel<<<1, 1024, 0, stream>>>(hist, binStart, gEV);
    scatter_kernel<<<(N_ANCH + 255) / 256, 256, 0, stream>>>(keys, binStart, cursor, scat);
    rank_kernel<<<(N_ANCH + 255) / 256, 256, 0, stream>>>(scat, binStart, hist, boxes, gEV,
                                                          topBoxes, (int*)&gEV[1]);
    maskT_kernel<<<dim3(NCHK, (NCHK + 3) / 4), 256, 0, stream>>>(topBoxes, gEV, S);
    nms_out_kernel<<<1, 1024, 0, stream>>>(topBoxes, gEV, S, out);
}

// Round 4
// 130.240 us; speedup vs baseline: 1.0082x; 1.0082x over previous
//
#include <hip/hip_runtime.h>
#include <stdint.h>

typedef unsigned long long u64;
typedef unsigned int u32;

#define N_ANCH 36864
#define WGRID 64
#define A_PER 9
#define KTOP 6000
#define NOUT 300
#define NBIN 5120       // max used bin = 4352 (binof), multiple of 1024 for scan
#define NCHK 94         // ceil(6000/64) = u64 words
#define NCH2 47         // chunk PAIRS per NMS round
#define NJ   6016       // padded j-stride of S (u64 words, 64-multiple >= 6000)
#define INF_BIN 0       // -inf / invalid scores
#define SLOTS 4         // sparse active-chunk slots per wave (64 total >= ~43 active)
#define SPILLCAP 32     // overflow actives (expected unused; correctness fallback)

// Raw barrier: LDS-drain only (HK/m201 pattern). Global prefetches stay in flight.
#define BARRIER_LDS() do {                                   \
    asm volatile("s_waitcnt lgkmcnt(0)" ::: "memory");       \
    __builtin_amdgcn_s_barrier();                            \
    asm volatile("" ::: "memory");                           \
} while (0)

// Base anchors from py-faster-rcnn generate_anchors (scales 8,16,32; ratios .5,1,2), exact integers.
__constant__ float c_ax1[9] = {-84.f,-176.f,-360.f,-56.f,-120.f,-248.f,-36.f,-80.f,-168.f};
__constant__ float c_ay1[9] = {-40.f,-88.f,-184.f,-56.f,-120.f,-248.f,-80.f,-168.f,-344.f};
__constant__ float c_aw[9]  = {184.f,368.f,736.f,128.f,256.f,512.f,88.f,176.f,352.f};
__constant__ float c_ah[9]  = {96.f,192.f,384.f,128.f,256.f,512.f,176.f,352.f,704.f};

// Monotone (order-preserving) bin of the ordered-float score word u = key>>32.
__device__ __forceinline__ u32 binof(u32 u) {
    if (u < 0x80000000u) return 0u;                          // -inf (invalid)
    if (u < 0xBF000000u) return 1u + ((u - 0x80000000u) >> 22);   // s<0.5 : 1..252
    return 256u + ((u - 0xBF000000u) >> 11);                 // s>=0.5: 256..4352
}

// 144 blocks x 256 threads = 36864.
__global__ __launch_bounds__(256) void proposal_kernel(const float* __restrict__ cls,
                                                       const float* __restrict__ dlt,
                                                       u64* __restrict__ keys,
                                                       float4* __restrict__ boxes,
                                                       u32* __restrict__ hist) {
    __shared__ u32 lh[NBIN];
    const int t = threadIdx.x;
    for (int b = t; b < NBIN; b += 256) lh[b] = 0;
    __syncthreads();

    int i = blockIdx.x * 256 + t;
    int a  = i % A_PER;
    int hw = i / A_PER;
    int wx = hw % WGRID;
    int hy = hw / WGRID;

    float2 lp = *(const float2*)(cls + hw * 18 + 2 * a);
    float l0 = lp.x, l1 = lp.y;
    float m  = fmaxf(l0, l1);
    float e0 = expf(l0 - m), e1 = expf(l1 - m);
    float s  = e1 / (e0 + e1);

    float4 dd = *(const float4*)(dlt + hw * 36 + 4 * a);
    float dx = dd.x, dy = dd.y, dw = dd.z, dh = dd.w;
    float aw = c_aw[a], ah = c_ah[a];
    float axc = (c_ax1[a] + 16.f * (float)wx) + 0.5f * aw;
    float ayc = (c_ay1[a] + 16.f * (float)hy) + 0.5f * ah;

    float pxc = dx * aw + axc;
    float pyc = dy * ah + ayc;
    float pw  = expf(dw) * aw;
    float ph  = expf(dh) * ah;
    float x1 = pxc - 0.5f * pw, y1 = pyc - 0.5f * ph;
    float x2 = pxc + 0.5f * pw, y2 = pyc + 0.5f * ph;
    x1 = fminf(fmaxf(x1, 0.f), 1023.f);
    x2 = fminf(fmaxf(x2, 0.f), 1023.f);
    y1 = fminf(fmaxf(y1, 0.f), 1023.f);
    y2 = fminf(fmaxf(y2, 0.f), 1023.f);
    bool valid = ((x2 - x1 + 1.f) >= 16.f) && ((y2 - y1 + 1.f) >= 16.f);
    float sc = valid ? s : -__builtin_huge_valf();

    u32 sb  = __float_as_uint(sc);
    u32 ord = (sb & 0x80000000u) ? ~sb : (sb | 0x80000000u);
    u64 key = ((u64)ord << 32) | (u32)(~(u32)i);
    keys[i]  = key;
    boxes[i] = make_float4(x1, y1, x2, y2);

    u64 infb = __ballot(!valid);
    if (valid) {
        atomicAdd(&lh[binof(ord)], 1u);
    } else {
        int lane = t & 63;
        if (lane == __builtin_ctzll(infb))
            atomicAdd(&lh[INF_BIN], (u32)__popcll(infb));
    }
    __syncthreads();
    for (int b = t; b < NBIN; b += 256) {
        u32 v = lh[b];
        if (v) atomicAdd(&hist[b], v);
    }
}

// Descending exclusive prefix over NBIN bins via shfl wave-scan (1 barrier).
__global__ __launch_bounds__(1024) void scan_kernel(const u32* __restrict__ hist,
                                                    u32* __restrict__ binStart,
                                                    u32* __restrict__ gEV) {
    __shared__ u32 wsum[16];
    const int t = threadIdx.x;
    const int lane = t & 63;
    const int v = t >> 6;
    if (t == 0) gEV[1] = KTOP;
    int hi = NBIN - 1 - 5 * t;   // thread t owns bins [hi-4 .. hi], descending
    u32 cnt[5];
    u32 sum = 0;
#pragma unroll
    for (int k = 0; k < 5; ++k) { cnt[k] = hist[hi - k]; sum += cnt[k]; }
    u32 s = sum;                 // inclusive wave scan (thread order == descending bins)
#pragma unroll
    for (int d = 1; d < 64; d <<= 1) {
        u32 x = __shfl_up(s, d, 64);
        if (lane >= d) s += x;
    }
    if (lane == 63) wsum[v] = s;
    __syncthreads();
    u32 base = 0;
#pragma unroll
    for (int q = 0; q < 16; ++q) {
        u32 x = wsum[q];
        if (q < v) base += x;
    }
    u32 run = base + s - sum;    // exclusive (sum of all higher bins)
#pragma unroll
    for (int k = 0; k < 5; ++k) {
        int b = hi - k;
        binStart[b] = run;
        u32 end = run + cnt[k];
        if (run < KTOP && end >= KTOP) gEV[0] = end;   // unique boundary bucket
        run = end;
    }
}

__global__ void scatter_kernel(const u64* __restrict__ keys,
                               const u32* __restrict__ binStart,
                               u32* __restrict__ cursor,
                               u64* __restrict__ scat) {
    int i = blockIdx.x * blockDim.x + threadIdx.x;
    if (i >= N_ANCH) return;
    u64 k = keys[i];
    u32 b = binof((u32)(k >> 32));
    u32 s = binStart[b];
    if (s < KTOP) {
        u32 p = s + atomicAdd(&cursor[b], 1u);
        scat[p] = k;
    }
}

__global__ void rank_kernel(const u64* __restrict__ scat,
                            const u32* __restrict__ binStart,
                            const u32* __restrict__ hist,
                            const float4* __restrict__ boxes,
                            const u32* __restrict__ gEV,
                            float4* __restrict__ topBoxes,
                            int* __restrict__ gV) {
    int i = blockIdx.x * blockDim.x + threadIdx.x;
    u32 E = gEV[0];
    if (i >= (int)E) return;
    u64 k = scat[i];
    u32 b = binof((u32)(k >> 32));
    u32 s = binStart[b], c = hist[b];
    u32 r = s;
    for (u32 j = s; j < s + c; ++j) r += (scat[j] > k) ? 1u : 0u;
    if (r < KTOP) {
        int idx = (int)(~(u32)k);
        topBoxes[r] = boxes[idx];
        if (!(k >> 63)) atomicMin(gV, (int)r);
    }
}

__device__ __forceinline__ bool iou_gt(float4 a, float areaA, float4 b, float areaB) {
    float ix1 = fmaxf(a.x, b.x), iy1 = fmaxf(a.y, b.y);
    float ix2 = fminf(a.z, b.z), iy2 = fminf(a.w, b.w);
    float iw = fmaxf(ix2 - ix1 + 1.0f, 0.0f);
    float ih = fmaxf(iy2 - iy1 + 1.0f, 0.0f);
    float inter = iw * ih;
    float iou = inter / (areaA + areaB - inter);
    return iou > 0.7f;
}

// TRANSPOSED suppression mask: S[w][j] bit b = (IoU(box_{64w+b}, box_j) > 0.7) && (64w+b < j).
__global__ __launch_bounds__(256) void maskT_kernel(const float4* __restrict__ topBoxes,
                                                    const u32* __restrict__ gEV,
                                                    u64* __restrict__ S) {
    const int V = (int)gEV[1];
    const int nch = (V + 63) >> 6;
    const int jc = blockIdx.x;               // j-chunk (column group of 64 boxes)
    const int w0 = blockIdx.y * 4;           // first i-word of this block
    if (jc >= nch || w0 > jc) return;        // only w <= jc needed (i < j)
    __shared__ float4 cb[256];
    __shared__ float  ca[256];
    const int t = threadIdx.x;
    const int lane = t & 63;
    {
        int ci = w0 * 64 + t;
        float4 b = (ci < V) ? topBoxes[ci] : make_float4(0.f, 0.f, -8.f, -8.f);
        cb[t] = b;
        ca[t] = (b.z - b.x + 1.f) * (b.w - b.y + 1.f);
    }
    __syncthreads();
    const int w = w0 + (t >> 6);
    if (w > jc || w >= nch) return;
    const int j = jc * 64 + lane;
    float4 bj = (j < V) ? topBoxes[j] : make_float4(0.f, 0.f, -8.f, -8.f);
    float aj = (bj.z - bj.x + 1.f) * (bj.w - bj.y + 1.f);
    const int s0 = (t >> 6) * 64;
    u64 m = 0;
#pragma unroll 4
    for (int b = 0; b < 64; ++b)
        if (iou_gt(bj, aj, cb[s0 + b], ca[s0 + b])) m |= (1ull << b);
    if (w == jc) m &= ((1ull << lane) - 1ull);   // diagonal word: keep only i < j
    S[(u64)w * NJ + j] = m;
}

// Single block, 1024 threads, EXACT greedy NMS over the transposed mask.
// v4: SPARSE active-chunk slots + 2 chunks per round (47 rounds, 1 raw barrier each).
// Data fact (round-1 FETCH analysis): only ~43 of 6000 boxes are kept -> most chunks
// contribute nothing. A chunk with kb!=0 is "claimed" into one of 64 register slots
// (4/wave, statically indexed); each round a wave only touches its claimed slots:
// acc |= pend & kw, one ballot per half, depth-1 prefetch of next round's words
// (addresses kept-independent). Intra-round pair resolve uses LDS-staged diagonal
// words dA/dAB/dB (72 KB, loaded once). Resolve is redundant across all 16 waves
// (identical inputs) so the only cross-wave data is supw -> ONE barrier per round.
__global__ __launch_bounds__(1024) void nms_out_kernel(const float4* __restrict__ topBoxes,
                                                       const u32* __restrict__ gEV,
                                                       const u64* __restrict__ S,
                                                       float* __restrict__ out) {
    __shared__ u64 dA[NCH2][64];             // S[2r][128r + l]        (diag of chunk A)
    __shared__ u64 dAB[NCH2][64];            // S[2r][128r + 64 + l]   (A suppressing B)
    __shared__ u64 dB[NCH2][64];             // S[2r+1][128r + 64 + l] (diag of chunk B)
    __shared__ u64 keepw[NCHK];
    __shared__ u64 supw[2][32];              // parity x (A in 0..15 | B in 16..31)
    __shared__ u64 spillK[SPILLCAP];
    __shared__ u32 spillW[SPILLCAP];
    __shared__ u32 wsum[16];
    const int t = threadIdx.x;
    const int lane = t & 63;
    const int v = t >> 6;                    // wave id, 16 waves
    const int V = (int)gEV[1];
    const int nch = (V + 63) >> 6;
    const int nr  = (nch + 1) >> 1;          // pair rounds
    if (t < NCHK) keepw[t] = 0;
    // stage all diagonal words once (coalesced; rows referenced are always written)
    for (int idx = t; idx < nr * 64; idx += 1024) {
        int r = idx >> 6, l = idx & 63;
        dA[r][l]  = S[(u64)(2 * r) * NJ + 128 * r + l];
        dAB[r][l] = S[(u64)(2 * r) * NJ + 128 * r + 64 + l];
        dB[r][l]  = S[(u64)(2 * r + 1) * NJ + 128 * r + 64 + l];
    }
    __syncthreads();

    // sparse slot state (all statically indexed -> registers)
    u64 kwS[SLOTS], pA[SLOTS], pB[SLOTS], aofs[SLOTS];
#pragma unroll
    for (int k = 0; k < SLOTS; ++k) { kwS[k] = 0; pA[k] = 0; pB[k] = 0; aofs[k] = 0; }
    int nslot = 0, nspill = 0, nkept = 0;    // uniform & identical across all waves

    for (int r = 0; r < nr; ++r) {
        const int par = r & 1;
        // --- acc: suppression of this round's 128 boxes by claimed earlier chunks
        u64 accA = 0, accB = 0;
#pragma unroll
        for (int k = 0; k < SLOTS; ++k) {
            if (nslot > 16 * k + v) { accA |= pA[k] & kwS[k]; accB |= pB[k] & kwS[k]; }
        }
        for (int s = 0; s < nspill; ++s) {   // overflow path (expected never taken)
            u64 kk = spillK[s];
            const u64* row = S + (u64)spillW[s] * NJ + 128 * r + lane;
            accA |= row[0] & kk; accB |= row[64] & kk;
        }
        u64 bA = __ballot(accA != 0ull), bB = __ballot(accB != 0ull);
        if (lane == 0) { supw[par][v] = bA; supw[par][16 + v] = bB; }
        // --- depth-1 prefetch refill for round r+1 (kept-independent addresses)
        if (r + 1 < nr) {
            u64 ofsn = (u64)(128 * (r + 1)) + lane;
#pragma unroll
            for (int k = 0; k < SLOTS; ++k)
                if (nslot > 16 * k + v) { pA[k] = S[aofs[k] + ofsn]; pB[k] = S[aofs[k] + ofsn + 64]; }
        }
        BARRIER_LDS();                       // the only barrier in the round
        // --- combine supw (identical in every wave)
        u64 x = supw[par][lane & 31];
#pragma unroll
        for (int m = 1; m < 16; m <<= 1) x |= __shfl_xor(x, m, 64);
        u64 rwA = __shfl(x, 0, 64);
        u64 rwB = __shfl(x, 16, 64);
        // --- resolve pair (redundant across waves; all values identical)
        int remA = V - 128 * r;
        int remB = remA - 64;
        u64 aliveA = (remA >= 64) ? ~0ull : ((remA <= 0) ? 0ull : ((1ull << remA) - 1ull));
        u64 aliveB = (remB >= 64) ? ~0ull : ((remB <= 0) ? 0ull : ((1ull << remB) - 1ull));
        u64 dAl = dA[r][lane], dABl = dAB[r][lane], dBl = dB[r][lane];
        u64 candA = ~rwA & aliveA, kbA = 0;
        while (candA) {
            int b = __builtin_ctzll(candA);
            kbA |= (1ull << b);
            candA &= ~(1ull << b);
            candA &= ~__ballot(((dAl >> b) & 1ull) != 0ull);
        }
        u64 supAB = __ballot((dABl & kbA) != 0ull);
        u64 candB = ~(rwB | supAB) & aliveB, kbB = 0;
        while (candB) {
            int b = __builtin_ctzll(candB);
            kbB |= (1ull << b);
            candB &= ~(1ull << b);
            candB &= ~__ballot(((dBl >> b) & 1ull) != 0ull);
        }
        if (t == 0) { keepw[2 * r] = kbA; if (2 * r + 1 < nch) keepw[2 * r + 1] = kbB; }
        // --- claims (uniform control flow; slot writes statically unrolled)
        bool sadd = false;
        if (kbA) {
            int so = nslot & 15, si = nslot >> 4;
            if (si < SLOTS) {
                if (v == so) {
#pragma unroll
                    for (int k = 0; k < SLOTS; ++k) if (k == si) {
                        kwS[k] = kbA; aofs[k] = (u64)(2 * r) * NJ;
                        if (r + 1 < nr) {
                            u64 o = (u64)(128 * (r + 1)) + lane;
                            pA[k] = S[aofs[k] + o]; pB[k] = S[aofs[k] + o + 64];
                        }
                    }
                }
                ++nslot;
            } else if (nspill < SPILLCAP) {
                if (v == 15 && lane == 0) { spillW[nspill] = 2 * r; spillK[nspill] = kbA; }
                ++nspill; sadd = true;
            }
        }
        if (kbB) {
            int so = nslot & 15, si = nslot >> 4;
            if (si < SLOTS) {
                if (v == so) {
#pragma unroll
                    for (int k = 0; k < SLOTS; ++k) if (k == si) {
                        kwS[k] = kbB; aofs[k] = (u64)(2 * r + 1) * NJ;
                        if (r + 1 < nr) {
                            u64 o = (u64)(128 * (r + 1)) + lane;
                            pA[k] = S[aofs[k] + o]; pB[k] = S[aofs[k] + o + 64];
                        }
                    }
                }
                ++nslot;
            } else if (nspill < SPILLCAP) {
                if (v == 15 && lane == 0) { spillW[nspill] = 2 * r + 1; spillK[nspill] = kbB; }
                ++nspill; sadd = true;
            }
        }
        if (sadd) BARRIER_LDS();             // make spill entries visible before next acc
        nkept += __popcll(kbA) + __popcll(kbB);
        if (nkept >= NOUT) break;            // uniform (all waves computed identical kb)
    }
    __syncthreads();                         // full drain once; keepw visible

    // Phase 2: out[pos] = kept boxes in rank order, then not-kept (suppressed or rank>=V)
    // in rank order, filling up to 300. shfl wave-scan (1 barrier).
    const int per = 6;                       // 1024*6 >= 6000
    int r0 = t * per;
    int r1 = min(r0 + per, KTOP);
    u32 cnt = 0;
    for (int r = r0; r < r1; ++r)
        cnt += (u32)((keepw[r >> 6] >> (r & 63)) & 1ull);
    u32 s = cnt;
#pragma unroll
    for (int d = 1; d < 64; d <<= 1) {
        u32 x = __shfl_up(s, d, 64);
        if (lane >= d) s += x;
    }
    if (lane == 63) wsum[v] = s;
    __syncthreads();
    u32 base = 0;
    u32 total = 0;
#pragma unroll
    for (int q = 0; q < 16; ++q) {
        u32 x = wsum[q];
        if (q < v) base += x;
        total += x;
    }
    const int n1 = min((int)total, NOUT);
    int kp = (int)(base + s - cnt);          // kept before r0
    for (int r = r0; r < r1; ++r) {
        int kept = (int)((keepw[r >> 6] >> (r & 63)) & 1ull);
        int pos = kept ? kp : (n1 + r - kp); // not-kept before r = r - kp
        if (pos < NOUT) {
            float4 b = topBoxes[r];
            out[pos * 5 + 0] = 0.f;
            out[pos * 5 + 1] = b.x;
            out[pos * 5 + 2] = b.y;
            out[pos * 5 + 3] = b.z;
            out[pos * 5 + 4] = b.w;
        }
        kp += kept;
    }
}

extern "C" void kernel_launch(void* const* d_in, const int* in_sizes, int n_in,
                              void* d_out, int out_size, void* d_ws, size_t ws_size,
                              hipStream_t stream) {
    const float* cls = (const float*)d_in[0];   // (1,64,64,18) f32
    const float* dlt = (const float*)d_in[1];   // (1,64,64,36) f32
    float* out = (float*)d_out;                 // 300x5 f32
    char* ws = (char*)d_ws;
    u64*    keys     = (u64*)   (ws);                    // 294912
    u64*    scat     = (u64*)   (ws + 294912);           // 294912
    float4* boxes    = (float4*)(ws + 589824);           // 589824
    float4* topBoxes = (float4*)(ws + 1179648);          // 96000
    u32*    hist     = (u32*)   (ws + 1275648);          // 20480
    u32*    cursor   = (u32*)   (ws + 1296128);          // 20480
    u32*    binStart = (u32*)   (ws + 1316608);          // 20480
    u32*    gEV      = (u32*)   (ws + 1337088);          // [0]=E, [1]=V (+pad)
    u64*    S        = (u64*)   (ws + 1337344);          // 4524032 (94 x 6016 words)

    hipMemsetAsync(hist, 0, 2 * NBIN * sizeof(u32), stream);   // hist + cursor
    proposal_kernel<<<144, 256, 0, stream>>>(cls, dlt, keys, boxes, hist);
    scan_kernel<<<1, 1024, 0, stream>>>(hist, binStart, gEV);
    scatter_kernel<<<(N_ANCH + 255) / 256, 256, 0, stream>>>(keys, binStart, cursor, scat);
    rank_kernel<<<(N_ANCH + 255) / 256, 256, 0, stream>>>(scat, binStart, hist, boxes, gEV,
                                                          topBoxes, (int*)&gEV[1]);
    maskT_kernel<<<dim3(NCHK, (NCHK + 3) / 4), 256, 0, stream>>>(topBoxes, gEV, S);
    nms_out_kernel<<<1, 1024, 0, stream>>>(topBoxes, gEV, S, out);
}

// Round 5
// 120.700 us; speedup vs baseline: 1.0879x; 1.0790x over previous
//
#include <hip/hip_runtime.h>
#include <stdint.h>

typedef unsigned long long u64;
typedef unsigned int u32;

#define N_ANCH 36864
#define WGRID 64
#define A_PER 9
#define KTOP 6000
#define NOUT 300
#define NBIN 5120       // max used bin = 4352 (binof), multiple of 1024 for scan
#define NCHK 94         // ceil(6000/64) = u64 words
#define NCH2 47         // chunk PAIRS per NMS round
#define NJ   6016       // padded j-stride of S (u64 words, 64-multiple >= 6000)
#define INF_BIN 0       // -inf / invalid scores
#define NMSW 4          // NMS waves (issue-bound: minimize redundant issue, keep slot spread)
#define SLOTS 10        // sparse active-chunk slots per wave (40 total)
#define SPILLCAP 64     // overflow actives; 40+64 >= 94 chunks -> always correct

// Raw barrier: LDS-drain only (HK/m201 pattern). Global prefetches stay in flight.
#define BARRIER_LDS() do {                                   \
    asm volatile("s_waitcnt lgkmcnt(0)" ::: "memory");       \
    __builtin_amdgcn_s_barrier();                            \
    asm volatile("" ::: "memory");                           \
} while (0)

// Base anchors from py-faster-rcnn generate_anchors (scales 8,16,32; ratios .5,1,2), exact integers.
__constant__ float c_ax1[9] = {-84.f,-176.f,-360.f,-56.f,-120.f,-248.f,-36.f,-80.f,-168.f};
__constant__ float c_ay1[9] = {-40.f,-88.f,-184.f,-56.f,-120.f,-248.f,-80.f,-168.f,-344.f};
__constant__ float c_aw[9]  = {184.f,368.f,736.f,128.f,256.f,512.f,88.f,176.f,352.f};
__constant__ float c_ah[9]  = {96.f,192.f,384.f,128.f,256.f,512.f,176.f,352.f,704.f};

// Monotone (order-preserving) bin of the ordered-float score word u = key>>32.
__device__ __forceinline__ u32 binof(u32 u) {
    if (u < 0x80000000u) return 0u;                          // -inf (invalid)
    if (u < 0xBF000000u) return 1u + ((u - 0x80000000u) >> 22);   // s<0.5 : 1..252
    return 256u + ((u - 0xBF000000u) >> 11);                 // s>=0.5: 256..4352
}

// 144 blocks x 256 threads = 36864.
__global__ __launch_bounds__(256) void proposal_kernel(const float* __restrict__ cls,
                                                       const float* __restrict__ dlt,
                                                       u64* __restrict__ keys,
                                                       float4* __restrict__ boxes,
                                                       u32* __restrict__ hist) {
    __shared__ u32 lh[NBIN];
    const int t = threadIdx.x;
    for (int b = t; b < NBIN; b += 256) lh[b] = 0;
    __syncthreads();

    int i = blockIdx.x * 256 + t;
    int a  = i % A_PER;
    int hw = i / A_PER;
    int wx = hw % WGRID;
    int hy = hw / WGRID;

    float2 lp = *(const float2*)(cls + hw * 18 + 2 * a);
    float l0 = lp.x, l1 = lp.y;
    float m  = fmaxf(l0, l1);
    float e0 = expf(l0 - m), e1 = expf(l1 - m);
    float s  = e1 / (e0 + e1);

    float4 dd = *(const float4*)(dlt + hw * 36 + 4 * a);
    float dx = dd.x, dy = dd.y, dw = dd.z, dh = dd.w;
    float aw = c_aw[a], ah = c_ah[a];
    float axc = (c_ax1[a] + 16.f * (float)wx) + 0.5f * aw;
    float ayc = (c_ay1[a] + 16.f * (float)hy) + 0.5f * ah;

    float pxc = dx * aw + axc;
    float pyc = dy * ah + ayc;
    float pw  = expf(dw) * aw;
    float ph  = expf(dh) * ah;
    float x1 = pxc - 0.5f * pw, y1 = pyc - 0.5f * ph;
    float x2 = pxc + 0.5f * pw, y2 = pyc + 0.5f * ph;
    x1 = fminf(fmaxf(x1, 0.f), 1023.f);
    x2 = fminf(fmaxf(x2, 0.f), 1023.f);
    y1 = fminf(fmaxf(y1, 0.f), 1023.f);
    y2 = fminf(fmaxf(y2, 0.f), 1023.f);
    bool valid = ((x2 - x1 + 1.f) >= 16.f) && ((y2 - y1 + 1.f) >= 16.f);
    float sc = valid ? s : -__builtin_huge_valf();

    u32 sb  = __float_as_uint(sc);
    u32 ord = (sb & 0x80000000u) ? ~sb : (sb | 0x80000000u);
    u64 key = ((u64)ord << 32) | (u32)(~(u32)i);
    keys[i]  = key;
    boxes[i] = make_float4(x1, y1, x2, y2);

    u64 infb = __ballot(!valid);
    if (valid) {
        atomicAdd(&lh[binof(ord)], 1u);
    } else {
        int lane = t & 63;
        if (lane == __builtin_ctzll(infb))
            atomicAdd(&lh[INF_BIN], (u32)__popcll(infb));
    }
    __syncthreads();
    for (int b = t; b < NBIN; b += 256) {
        u32 v = lh[b];
        if (v) atomicAdd(&hist[b], v);
    }
}

// Descending exclusive prefix over NBIN bins via shfl wave-scan (1 barrier).
__global__ __launch_bounds__(1024) void scan_kernel(const u32* __restrict__ hist,
                                                    u32* __restrict__ binStart,
                                                    u32* __restrict__ gEV) {
    __shared__ u32 wsum[16];
    const int t = threadIdx.x;
    const int lane = t & 63;
    const int v = t >> 6;
    if (t == 0) gEV[1] = KTOP;
    int hi = NBIN - 1 - 5 * t;   // thread t owns bins [hi-4 .. hi], descending
    u32 cnt[5];
    u32 sum = 0;
#pragma unroll
    for (int k = 0; k < 5; ++k) { cnt[k] = hist[hi - k]; sum += cnt[k]; }
    u32 s = sum;                 // inclusive wave scan (thread order == descending bins)
#pragma unroll
    for (int d = 1; d < 64; d <<= 1) {
        u32 x = __shfl_up(s, d, 64);
        if (lane >= d) s += x;
    }
    if (lane == 63) wsum[v] = s;
    __syncthreads();
    u32 base = 0;
#pragma unroll
    for (int q = 0; q < 16; ++q) {
        u32 x = wsum[q];
        if (q < v) base += x;
    }
    u32 run = base + s - sum;    // exclusive (sum of all higher bins)
#pragma unroll
    for (int k = 0; k < 5; ++k) {
        int b = hi - k;
        binStart[b] = run;
        u32 end = run + cnt[k];
        if (run < KTOP && end >= KTOP) gEV[0] = end;   // unique boundary bucket
        run = end;
    }
}

__global__ void scatter_kernel(const u64* __restrict__ keys,
                               const u32* __restrict__ binStart,
                               u32* __restrict__ cursor,
                               u64* __restrict__ scat) {
    int i = blockIdx.x * blockDim.x + threadIdx.x;
    if (i >= N_ANCH) return;
    u64 k = keys[i];
    u32 b = binof((u32)(k >> 32));
    u32 s = binStart[b];
    if (s < KTOP) {
        u32 p = s + atomicAdd(&cursor[b], 1u);
        scat[p] = k;
    }
}

__global__ void rank_kernel(const u64* __restrict__ scat,
                            const u32* __restrict__ binStart,
                            const u32* __restrict__ hist,
                            const float4* __restrict__ boxes,
                            const u32* __restrict__ gEV,
                            float4* __restrict__ topBoxes,
                            int* __restrict__ gV) {
    int i = blockIdx.x * blockDim.x + threadIdx.x;
    u32 E = gEV[0];
    if (i >= (int)E) return;
    u64 k = scat[i];
    u32 b = binof((u32)(k >> 32));
    u32 s = binStart[b], c = hist[b];
    u32 r = s;
    for (u32 j = s; j < s + c; ++j) r += (scat[j] > k) ? 1u : 0u;
    if (r < KTOP) {
        int idx = (int)(~(u32)k);
        topBoxes[r] = boxes[idx];
        if (!(k >> 63)) atomicMin(gV, (int)r);
    }
}

__device__ __forceinline__ bool iou_gt(float4 a, float areaA, float4 b, float areaB) {
    float ix1 = fmaxf(a.x, b.x), iy1 = fmaxf(a.y, b.y);
    float ix2 = fminf(a.z, b.z), iy2 = fminf(a.w, b.w);
    float iw = fmaxf(ix2 - ix1 + 1.0f, 0.0f);
    float ih = fmaxf(iy2 - iy1 + 1.0f, 0.0f);
    float inter = iw * ih;
    float iou = inter / (areaA + areaB - inter);
    return iou > 0.7f;
}

// TRANSPOSED suppression mask: S[w][j] bit b = (IoU(box_{64w+b}, box_j) > 0.7) && (64w+b < j).
__global__ __launch_bounds__(256) void maskT_kernel(const float4* __restrict__ topBoxes,
                                                    const u32* __restrict__ gEV,
                                                    u64* __restrict__ S) {
    const int V = (int)gEV[1];
    const int nch = (V + 63) >> 6;
    const int jc = blockIdx.x;               // j-chunk (column group of 64 boxes)
    const int w0 = blockIdx.y * 4;           // first i-word of this block
    if (jc >= nch || w0 > jc) return;        // only w <= jc needed (i < j)
    __shared__ float4 cb[256];
    __shared__ float  ca[256];
    const int t = threadIdx.x;
    const int lane = t & 63;
    {
        int ci = w0 * 64 + t;
        float4 b = (ci < V) ? topBoxes[ci] : make_float4(0.f, 0.f, -8.f, -8.f);
        cb[t] = b;
        ca[t] = (b.z - b.x + 1.f) * (b.w - b.y + 1.f);
    }
    __syncthreads();
    const int w = w0 + (t >> 6);
    if (w > jc || w >= nch) return;
    const int j = jc * 64 + lane;
    float4 bj = (j < V) ? topBoxes[j] : make_float4(0.f, 0.f, -8.f, -8.f);
    float aj = (bj.z - bj.x + 1.f) * (bj.w - bj.y + 1.f);
    const int s0 = (t >> 6) * 64;
    u64 m = 0;
#pragma unroll 4
    for (int b = 0; b < 64; ++b)
        if (iou_gt(bj, aj, cb[s0 + b], ca[s0 + b])) m |= (1ull << b);
    if (w == jc) m &= ((1ull << lane) - 1ull);   // diagonal word: keep only i < j
    S[(u64)w * NJ + j] = m;
}

// Single block, 256 threads (4 waves), EXACT greedy NMS over the transposed mask.
// v5: same sparse-slot pair-round structure as v4 (which passed), but with FOUR waves.
// v4's post-mortem: per-chunk cost ~1040 cy was pure instruction-issue + DS-pipe from
// 16-way REDUNDANT execution. Issue cost = slot-work (fixed total) + per-wave fixed
// overhead x W + redundant resolve x W -> W=4 minimizes. Spill acc is also
// deduplicated across waves (s%4==v). One raw barrier per round (parity supw).
__global__ __launch_bounds__(256) void nms_out_kernel(const float4* __restrict__ topBoxes,
                                                      const u32* __restrict__ gEV,
                                                      const u64* __restrict__ S,
                                                      float* __restrict__ out) {
    __shared__ u64 dA[NCH2][64];             // S[2r][128r + l]        (diag of chunk A)
    __shared__ u64 dAB[NCH2][64];            // S[2r][128r + 64 + l]   (A suppressing B)
    __shared__ u64 dB[NCH2][64];             // S[2r+1][128r + 64 + l] (diag of chunk B)
    __shared__ u64 keepw[NCHK];
    __shared__ u64 supw[2][2 * NMSW];        // parity x (A in 0..3 | B in 4..7)
    __shared__ u64 spillK[SPILLCAP];
    __shared__ u32 spillW[SPILLCAP];
    __shared__ u32 wsum[NMSW];
    const int t = threadIdx.x;
    const int lane = t & 63;
    const int v = t >> 6;                    // wave id, 4 waves
    const int V = (int)gEV[1];
    const int nch = (V + 63) >> 6;
    const int nr  = (nch + 1) >> 1;          // pair rounds
    if (t < NCHK) keepw[t] = 0;
    // stage all diagonal words once (coalesced; any referenced-but-unwritten row is dead)
    for (int idx = t; idx < nr * 64; idx += 256) {
        int r = idx >> 6, l = idx & 63;
        dA[r][l]  = S[(u64)(2 * r) * NJ + 128 * r + l];
        dAB[r][l] = S[(u64)(2 * r) * NJ + 128 * r + 64 + l];
        dB[r][l]  = S[(u64)(2 * r + 1) * NJ + 128 * r + 64 + l];
    }
    __syncthreads();

    // sparse slot state (all statically indexed -> registers)
    u64 kwS[SLOTS], pA[SLOTS], pB[SLOTS], aofs[SLOTS];
#pragma unroll
    for (int k = 0; k < SLOTS; ++k) { kwS[k] = 0; pA[k] = 0; pB[k] = 0; aofs[k] = 0; }
    int nslot = 0, nspill = 0, nkept = 0;    // uniform & identical across all waves

    for (int r = 0; r < nr; ++r) {
        const int par = r & 1;
        // --- acc: suppression of this round's 128 boxes by claimed earlier chunks
        u64 accA = 0, accB = 0;
#pragma unroll
        for (int k = 0; k < SLOTS; ++k) {
            if (nslot > NMSW * k + v) { accA |= pA[k] & kwS[k]; accB |= pB[k] & kwS[k]; }
        }
        for (int s = v; s < nspill; s += NMSW) {   // overflow path, deduped across waves
            u64 kk = spillK[s];
            const u64* row = S + (u64)spillW[s] * NJ + 128 * r + lane;
            accA |= row[0] & kk; accB |= row[64] & kk;
        }
        u64 bA = __ballot(accA != 0ull), bB = __ballot(accB != 0ull);
        if (lane == 0) { supw[par][v] = bA; supw[par][NMSW + v] = bB; }
        // --- depth-1 prefetch refill for round r+1 (kept-independent addresses)
        if (r + 1 < nr) {
            u64 ofsn = (u64)(128 * (r + 1)) + lane;
#pragma unroll
            for (int k = 0; k < SLOTS; ++k)
                if (nslot > NMSW * k + v) { pA[k] = S[aofs[k] + ofsn]; pB[k] = S[aofs[k] + ofsn + 64]; }
        }
        BARRIER_LDS();                       // the only barrier in the round
        // --- combine supw: uniform-address broadcast reads (identical in every wave)
        u64 rwA = supw[par][0] | supw[par][1] | supw[par][2] | supw[par][3];
        u64 rwB = supw[par][4] | supw[par][5] | supw[par][6] | supw[par][7];
        // --- resolve pair (redundant across 4 waves; all values identical)
        int remA = V - 128 * r;
        int remB = remA - 64;
        u64 aliveA = (remA >= 64) ? ~0ull : ((remA <= 0) ? 0ull : ((1ull << remA) - 1ull));
        u64 aliveB = (remB >= 64) ? ~0ull : ((remB <= 0) ? 0ull : ((1ull << remB) - 1ull));
        u64 dAl = dA[r][lane], dABl = dAB[r][lane], dBl = dB[r][lane];
        u64 candA = ~rwA & aliveA, kbA = 0;
        while (candA) {
            int b = __builtin_ctzll(candA);
            kbA |= (1ull << b);
            candA &= ~(1ull << b);
            candA &= ~__ballot(((dAl >> b) & 1ull) != 0ull);
        }
        u64 supAB = __ballot((dABl & kbA) != 0ull);
        u64 candB = ~(rwB | supAB) & aliveB, kbB = 0;
        while (candB) {
            int b = __builtin_ctzll(candB);
            kbB |= (1ull << b);
            candB &= ~(1ull << b);
            candB &= ~__ballot(((dBl >> b) & 1ull) != 0ull);
        }
        if (t == 0) { keepw[2 * r] = kbA; if (2 * r + 1 < nch) keepw[2 * r + 1] = kbB; }
        // --- claims (uniform control flow; slot writes statically unrolled)
        bool sadd = false;
        if (kbA) {
            int so = nslot & (NMSW - 1), si = nslot >> 2;
            if (si < SLOTS) {
                if (v == so) {
#pragma unroll
                    for (int k = 0; k < SLOTS; ++k) if (k == si) {
                        kwS[k] = kbA; aofs[k] = (u64)(2 * r) * NJ;
                        if (r + 1 < nr) {
                            u64 o = (u64)(128 * (r + 1)) + lane;
                            pA[k] = S[aofs[k] + o]; pB[k] = S[aofs[k] + o + 64];
                        }
                    }
                }
                ++nslot;
            } else if (nspill < SPILLCAP) {
                if (v == NMSW - 1 && lane == 0) { spillW[nspill] = 2 * r; spillK[nspill] = kbA; }
                ++nspill; sadd = true;
            }
        }
        if (kbB) {
            int so = nslot & (NMSW - 1), si = nslot >> 2;
            if (si < SLOTS) {
                if (v == so) {
#pragma unroll
                    for (int k = 0; k < SLOTS; ++k) if (k == si) {
                        kwS[k] = kbB; aofs[k] = (u64)(2 * r + 1) * NJ;
                        if (r + 1 < nr) {
                            u64 o = (u64)(128 * (r + 1)) + lane;
                            pA[k] = S[aofs[k] + o]; pB[k] = S[aofs[k] + o + 64];
                        }
                    }
                }
                ++nslot;
            } else if (nspill < SPILLCAP) {
                if (v == NMSW - 1 && lane == 0) { spillW[nspill] = 2 * r + 1; spillK[nspill] = kbB; }
                ++nspill; sadd = true;
            }
        }
        if (sadd) BARRIER_LDS();             // make spill entries visible before next acc
        nkept += __popcll(kbA) + __popcll(kbB);
        if (nkept >= NOUT) break;            // uniform (all waves computed identical kb)
    }
    __syncthreads();                         // full drain once; keepw visible

    // Phase 2: out[pos] = kept boxes in rank order, then not-kept (suppressed or rank>=V)
    // in rank order, filling up to 300. shfl wave-scan (1 barrier). 256 threads: per=24.
    const int per = 24;                      // 256*24 >= 6000
    int r0 = t * per;
    int r1 = min(r0 + per, KTOP);
    u32 cnt = 0;
    for (int r = r0; r < r1; ++r)
        cnt += (u32)((keepw[r >> 6] >> (r & 63)) & 1ull);
    u32 s = cnt;
#pragma unroll
    for (int d = 1; d < 64; d <<= 1) {
        u32 x = __shfl_up(s, d, 64);
        if (lane >= d) s += x;
    }
    if (lane == 63) wsum[v] = s;
    __syncthreads();
    u32 base = 0;
    u32 total = 0;
#pragma unroll
    for (int q = 0; q < NMSW; ++q) {
        u32 x = wsum[q];
        if (q < v) base += x;
        total += x;
    }
    const int n1 = min((int)total, NOUT);
    int kp = (int)(base + s - cnt);          // kept before r0
    for (int r = r0; r < r1; ++r) {
        int kept = (int)((keepw[r >> 6] >> (r & 63)) & 1ull);
        int pos = kept ? kp : (n1 + r - kp); // not-kept before r = r - kp
        if (pos < NOUT) {
            float4 b = topBoxes[r];
            out[pos * 5 + 0] = 0.f;
            out[pos * 5 + 1] = b.x;
            out[pos * 5 + 2] = b.y;
            out[pos * 5 + 3] = b.z;
            out[pos * 5 + 4] = b.w;
        }
        kp += kept;
    }
}

extern "C" void kernel_launch(void* const* d_in, const int* in_sizes, int n_in,
                              void* d_out, int out_size, void* d_ws, size_t ws_size,
                              hipStream_t stream) {
    const float* cls = (const float*)d_in[0];   // (1,64,64,18) f32
    const float* dlt = (const float*)d_in[1];   // (1,64,64,36) f32
    float* out = (float*)d_out;                 // 300x5 f32
    char* ws = (char*)d_ws;
    u64*    keys     = (u64*)   (ws);                    // 294912
    u64*    scat     = (u64*)   (ws + 294912);           // 294912
    float4* boxes    = (float4*)(ws + 589824);           // 589824
    float4* topBoxes = (float4*)(ws + 1179648);          // 96000
    u32*    hist     = (u32*)   (ws + 1275648);          // 20480
    u32*    cursor   = (u32*)   (ws + 1296128);          // 20480
    u32*    binStart = (u32*)   (ws + 1316608);          // 20480
    u32*    gEV      = (u32*)   (ws + 1337088);          // [0]=E, [1]=V (+pad)
    u64*    S        = (u64*)   (ws + 1337344);          // 4524032 (94 x 6016 words)

    hipMemsetAsync(hist, 0, 2 * NBIN * sizeof(u32), stream);   // hist + cursor
    proposal_kernel<<<144, 256, 0, stream>>>(cls, dlt, keys, boxes, hist);
    scan_kernel<<<1, 1024, 0, stream>>>(hist, binStart, gEV);
    scatter_kernel<<<(N_ANCH + 255) / 256, 256, 0, stream>>>(keys, binStart, cursor, scat);
    rank_kernel<<<(N_ANCH + 255) / 256, 256, 0, stream>>>(scat, binStart, hist, boxes, gEV,
                                                          topBoxes, (int*)&gEV[1]);
    maskT_kernel<<<dim3(NCHK, (NCHK + 3) / 4), 256, 0, stream>>>(topBoxes, gEV, S);
    nms_out_kernel<<<1, 256, 0, stream>>>(topBoxes, gEV, S, out);
}